// Round 9
// baseline (438.728 us; speedup 1.0000x reference)
//
#include <hip/hip_runtime.h>
#include <hip/hip_fp16.h>

#define D 128
#define TPAD 136         // halves; GEMM LDS row stride
#define NPB 256          // nodes per bucket (dst >> 8)
#define KMAX 512         // max buckets (n <= 131072)
#define CHUNK 4096       // edges per block in bucket passes
#define SCAP 6144        // csr_build LDS edge cap (bucket avg 4092, sd ~64)
#define SRCMASK 0x1FFFF  // low 17 bits: src id (n <= 131072)

typedef _Float16 half_t;
typedef _Float16 f16x8 __attribute__((ext_vector_type(8)));
typedef float f32x4 __attribute__((ext_vector_type(4)));

// ---------------- setup: W packs + bucket histogram in ONE kernel ----------------

__global__ __launch_bounds__(256) void setup_kernel(const float* __restrict__ W1,
                                                    const float* __restrict__ W2,
                                                    const float* __restrict__ W3,
                                                    half_t* __restrict__ Wf1,
                                                    half_t* __restrict__ Wf2,
                                                    half_t* __restrict__ Wf3,
                                                    const int* __restrict__ dst,
                                                    int* __restrict__ bucket_cnt, int E) {
    __shared__ int scnt[KMAX];
    int b = blockIdx.x, t = threadIdx.x;
    if (b < 96) {
        const float* W = (b < 32) ? W1 : (b < 64) ? W2 : W3;
        half_t* Wf = (b < 32) ? Wf1 : (b < 64) ? Wf2 : Wf3;
        int bb = b & 31;                 // 0..31 = (s, tq)
        int s = bb >> 3, tq = bb & 7;
        for (int e = t; e < 512; e += 256) {
            int l = e >> 3, j = e & 7;
            int k = s * 32 + ((l >> 4) & 3) * 4 + (j & 3) + ((j >> 2) << 4);
            int nn = tq * 16 + (l & 15);
            Wf[(size_t)((s * 8 + tq) * 64 + l) * 8 + j] = (half_t)W[k * 128 + nn];
        }
    } else if (b >= 98) {
        for (int i = t; i < KMAX; i += 256) scnt[i] = 0;
        __syncthreads();
        int base = (b - 98) * CHUNK;
        int nE = min(CHUNK, E - base);
        for (int i = t; i < nE; i += 256)
            atomicAdd(&scnt[dst[base + i] >> 8], 1);
        __syncthreads();
        for (int i = t; i < KMAX; i += 256)
            if (scnt[i]) atomicAdd(&bucket_cnt[i], scnt[i]);
    }
}

// Exclusive scan of bucket_cnt[K] -> bucket_ptr[K+1], bucket_cur[K]=bucket_ptr[K]
__global__ __launch_bounds__(KMAX) void bucket_scan_kernel(const int* __restrict__ bucket_cnt,
                                                           int* __restrict__ bucket_ptr,
                                                           int* __restrict__ bucket_cur,
                                                           int K, int E) {
    __shared__ int sh[KMAX];
    int t = threadIdx.x;
    int v = (t < K) ? bucket_cnt[t] : 0;
    sh[t] = v;
    __syncthreads();
    for (int off = 1; off < KMAX; off <<= 1) {
        int add = (t >= off) ? sh[t - off] : 0;
        __syncthreads();
        sh[t] += add;
        __syncthreads();
    }
    if (t < K) {
        int ex = sh[t] - v;
        bucket_ptr[t] = ex;
        bucket_cur[t] = ex;
    }
    if (t == 0) bucket_ptr[K] = E;
}

// R14: bdata packed to ONE int: src | (dst&255)<<17 — halves partition traffic.
__global__ __launch_bounds__(256) void bucket_scatter_kernel(const int* __restrict__ src,
                                                             const int* __restrict__ dst,
                                                             int* __restrict__ bucket_cur,
                                                             int* __restrict__ bpack, int E) {
    __shared__ int sdst[CHUNK];     // 16 KB
    __shared__ int scnt[KMAX];      // 2 KB
    __shared__ int sbase[KMAX];     // 2 KB
    int t = threadIdx.x;
    int base = blockIdx.x * CHUNK;
    int nE = min(CHUNK, E - base);
    for (int i = t; i < KMAX; i += 256) scnt[i] = 0;
    __syncthreads();
    for (int i = t; i < nE; i += 256) {
        int d = dst[base + i];
        sdst[i] = d;
        atomicAdd(&scnt[d >> 8], 1);
    }
    __syncthreads();
    for (int i = t; i < KMAX; i += 256) {
        int c = scnt[i];
        sbase[i] = c ? atomicAdd(&bucket_cur[i], c) : 0;
        scnt[i] = 0;                // reuse as local cursor
    }
    __syncthreads();
    for (int i = t; i < nE; i += 256) {
        int d = sdst[i];
        int b = d >> 8;
        int pos = sbase[b] + atomicAdd(&scnt[b], 1);
        bpack[pos] = src[base + i] | ((d & 255) << 17);
    }
}

// Fused count+scan+fill on packed edges (LDS 26 KB -> better occupancy).
__global__ __launch_bounds__(256) void csr_build_kernel(const int* __restrict__ bpack,
                                                        const int* __restrict__ bucket_ptr,
                                                        int* __restrict__ row_ptr,
                                                        float* __restrict__ dis,
                                                        int* __restrict__ csr_src,
                                                        int n, int E, int K) {
    __shared__ int scnt[NPB];
    __shared__ int sh[NPB];
    __shared__ int sedge[SCAP];     // 24 KB
    int b = blockIdx.x;
    int node0 = b << 8;
    int nn = min(NPB, n - node0);
    int t = threadIdx.x;
    int p0 = bucket_ptr[b], p1 = bucket_ptr[b + 1];
    int cnt = p1 - p0;
    bool stage = (cnt <= SCAP);     // wave-uniform
    scnt[t] = 0;
    __syncthreads();
    for (int i = t; i < cnt; i += 256) {
        int e = bpack[p0 + i];
        if (stage) sedge[i] = e;
        atomicAdd(&scnt[(e >> 17) & 255], 1);
    }
    __syncthreads();
    int v = scnt[t];
    sh[t] = v;
    __syncthreads();
    for (int off = 1; off < NPB; off <<= 1) {
        int add = (t >= off) ? sh[t - off] : 0;
        __syncthreads();
        sh[t] += add;
        __syncthreads();
    }
    int rowbase = p0 + sh[t] - v;   // exclusive
    if (t < nn) {
        row_ptr[node0 + t] = rowbase;
        dis[node0 + t] = rsqrtf((float)(v + 1)); // +1 self-loop
    }
    if (b == K - 1 && t == 0) row_ptr[n] = E;
    scnt[t] = rowbase;              // reuse as cursor
    __syncthreads();
    for (int i = t; i < cnt; i += 256) {
        int e = stage ? sedge[i] : bpack[p0 + i];
        int pos = atomicAdd(&scnt[(e >> 17) & 255], 1);
        csr_src[pos] = e & SRCMASK;
    }
}

// ---------------- GEMM (MFMA): C[n x 128] = fp16( dis[row] * (A @ W) ) ----------
// R14: 128-row block = two 64-row sub-tiles sharing one W-fragment load stream
// (halves per-row W traffic + VMEM instruction count; halves grid).

__device__ __forceinline__ void gemm_mfma_loop2(const half_t* sA, const half_t* __restrict__ Wf,
                                                f32x4 acc0[8], f32x4 acc1[8], int l, int w) {
    int m = l & 15, g = l >> 4;
    int R = w * 16;
    const f16x8* WF = (const f16x8*)Wf;
#pragma unroll
    for (int s = 0; s < 4; ++s) {        // K steps of 32
        union { f16x8 v; float2 f2[2]; } a0, a1;
        int off0 = (R + m) * TPAD + s * 32 + 4 * g;
        int off1 = off0 + 64 * TPAD;
        a0.f2[0] = *(const float2*)&sA[off0];        // k +0..3
        a0.f2[1] = *(const float2*)&sA[off0 + 16];   // k +16..19
        a1.f2[0] = *(const float2*)&sA[off1];
        a1.f2[1] = *(const float2*)&sA[off1 + 16];
#pragma unroll
        for (int t = 0; t < 8; ++t) {
            f16x8 bf = WF[(size_t)(s * 8 + t) * 64 + l];
            acc0[t] = __builtin_amdgcn_mfma_f32_16x16x32_f16(a0.v, bf, acc0[t], 0, 0, 0);
            acc1[t] = __builtin_amdgcn_mfma_f32_16x16x32_f16(a1.v, bf, acc1[t], 0, 0, 0);
        }
    }
}

__device__ __forceinline__ void gemm_epilogue2(half_t* sA, int tid, int base,
                                               const float* __restrict__ dis,
                                               half_t* __restrict__ C, int n,
                                               f32x4 acc0[8], f32x4 acc1[8], int l, int w) {
    int m = l & 15, g = l >> 4;
    int R = w * 16;
    int r0 = base + R + 4 * g;           // tile0 rows
    int r1 = r0 + 64;                    // tile1 rows
    float dd0[4], dd1[4];
#pragma unroll
    for (int r = 0; r < 4; ++r) {
        dd0[r] = (r0 + r < n) ? dis[r0 + r] : 0.f;
        dd1[r] = (r1 + r < n) ? dis[r1 + r] : 0.f;
    }
    __syncthreads();            // all frag reads done before clobbering sA
#pragma unroll
    for (int t = 0; t < 8; ++t) {
#pragma unroll
        for (int r = 0; r < 4; ++r) {
            sA[(R + 4 * g + r) * TPAD + t * 16 + m] = (half_t)(acc0[t][r] * dd0[r]);
            sA[(64 + R + 4 * g + r) * TPAD + t * 16 + m] = (half_t)(acc1[t][r] * dd1[r]);
        }
    }
    __syncthreads();
#pragma unroll
    for (int q = 0; q < 8; ++q) {
        int f4 = q * 256 + tid;         // 0..2047 ; 16 float4 per row, 128 rows
        int r = f4 >> 4, c = f4 & 15;
        int row = base + r;
        if (row < n)
            *(float4*)&C[(size_t)row * D + c * 8] = *(const float4*)&sA[r * TPAD + c * 8];
    }
}

__global__ __launch_bounds__(256) void gemm_mfma_f32in(const float* __restrict__ A,
                                                       const half_t* __restrict__ Wf,
                                                       const float* __restrict__ dis,
                                                       half_t* __restrict__ C, int n) {
    __shared__ half_t sA[128 * TPAD];    // 34 KB
    int tid = threadIdx.x;
    int base = blockIdx.x * 128;

    const float4* A4 = (const float4*)A;     // row stride = 32 float4
#pragma unroll
    for (int it = 0; it < 16; ++it) {
        int idx = it * 256 + tid;            // 0..4095
        int r = idx >> 5, kq = idx & 31;
        int grow = base + r;
        float4 va = (grow < n) ? A4[(size_t)grow * 32 + kq]
                               : make_float4(0.f, 0.f, 0.f, 0.f);
        union { half_t h[4]; float2 f2; } pk;
        pk.h[0] = (half_t)va.x; pk.h[1] = (half_t)va.y;
        pk.h[2] = (half_t)va.z; pk.h[3] = (half_t)va.w;
        *(float2*)&sA[r * TPAD + kq * 4] = pk.f2;
    }
    __syncthreads();

    int l = tid & 63, w = tid >> 6;
    f32x4 acc0[8], acc1[8];
#pragma unroll
    for (int t = 0; t < 8; ++t) {
        acc0[t] = (f32x4){0.f, 0.f, 0.f, 0.f};
        acc1[t] = (f32x4){0.f, 0.f, 0.f, 0.f};
    }
    gemm_mfma_loop2(sA, Wf, acc0, acc1, l, w);
    gemm_epilogue2(sA, tid, base, dis, C, n, acc0, acc1, l, w);
}

__global__ __launch_bounds__(256) void gemm_mfma_f16in(const half_t* __restrict__ A,
                                                       const half_t* __restrict__ Wf,
                                                       const float* __restrict__ dis,
                                                       half_t* __restrict__ C, int n) {
    __shared__ half_t sA[128 * TPAD];    // 34 KB
    int tid = threadIdx.x;
    int base = blockIdx.x * 128;

    const float4* A4 = (const float4*)A;     // fp16 row = 16 float4
#pragma unroll
    for (int it = 0; it < 8; ++it) {
        int idx = it * 256 + tid;            // 0..2047
        int r = idx >> 4, c16 = idx & 15;
        int grow = base + r;
        float4 va = (grow < n) ? A4[(size_t)grow * 16 + c16]
                               : make_float4(0.f, 0.f, 0.f, 0.f);
        *(float4*)&sA[r * TPAD + c16 * 8] = va;
    }
    __syncthreads();

    int l = tid & 63, w = tid >> 6;
    f32x4 acc0[8], acc1[8];
#pragma unroll
    for (int t = 0; t < 8; ++t) {
        acc0[t] = (f32x4){0.f, 0.f, 0.f, 0.f};
        acc1[t] = (f32x4){0.f, 0.f, 0.f, 0.f};
    }
    gemm_mfma_loop2(sA, Wf, acc0, acc1, l, w);
    gemm_epilogue2(sA, tid, base, dis, C, n, acc0, acc1, l, w);
}

// ---------------- Aggregation: out[i] = dis_i*(H'[i] + sum_e H'[src_e]) + b ----------
// R11-proven. F16OUT: write relu'd fp16 (layers 1-2).

template <bool F16OUT>
__global__ __launch_bounds__(256) void aggregate_kernel(const __half2* __restrict__ Hs,
                                                        const int* __restrict__ row_ptr,
                                                        const int* __restrict__ csr_src,
                                                        const float* __restrict__ dis,
                                                        const float* __restrict__ b,
                                                        void* __restrict__ outv, int n) {
    int node = blockIdx.x * 4 + (threadIdx.x >> 6);
    if (node >= n) return;
    int lane = threadIdx.x & 63;

    float2 s0 = __half22float2(Hs[(size_t)node * 64 + lane]);
    float accx = s0.x, accy = s0.y;                     // self-loop term H'[i]

    int p0 = row_ptr[node], p1 = row_ptr[node + 1];
    int p = p0;
    int nb8 = (p1 - p0) >> 3;
    if (nb8 > 0) {
        int idx[8];
#pragma unroll
        for (int u = 0; u < 8; ++u) idx[u] = csr_src[p + u];
        for (int bb = 1; bb < nb8; ++bb) {
            int nxt[8];
#pragma unroll
            for (int u = 0; u < 8; ++u) nxt[u] = csr_src[p + 8 + u];   // prefetch
            __half2 v[8];
#pragma unroll
            for (int u = 0; u < 8; ++u) v[u] = Hs[(size_t)idx[u] * 64 + lane];
#pragma unroll
            for (int u = 0; u < 8; ++u) {
                float2 f = __half22float2(v[u]);
                accx += f.x; accy += f.y;
            }
#pragma unroll
            for (int u = 0; u < 8; ++u) idx[u] = nxt[u];
            p += 8;
        }
        {
            __half2 v[8];
#pragma unroll
            for (int u = 0; u < 8; ++u) v[u] = Hs[(size_t)idx[u] * 64 + lane];
#pragma unroll
            for (int u = 0; u < 8; ++u) {
                float2 f = __half22float2(v[u]);
                accx += f.x; accy += f.y;
            }
            p += 8;
        }
    }
    for (; p + 4 <= p1; p += 4) {
        int s0i = csr_src[p + 0];
        int s1i = csr_src[p + 1];
        int s2i = csr_src[p + 2];
        int s3i = csr_src[p + 3];
        __half2 v0 = Hs[(size_t)s0i * 64 + lane];
        __half2 v1 = Hs[(size_t)s1i * 64 + lane];
        __half2 v2 = Hs[(size_t)s2i * 64 + lane];
        __half2 v3 = Hs[(size_t)s3i * 64 + lane];
        float2 f0 = __half22float2(v0), f1 = __half22float2(v1);
        float2 f2 = __half22float2(v2), f3 = __half22float2(v3);
        accx += f0.x; accy += f0.y;
        accx += f1.x; accy += f1.y;
        accx += f2.x; accy += f2.y;
        accx += f3.x; accy += f3.y;
    }
    for (; p < p1; ++p) {
        int s = csr_src[p];
        float2 f = __half22float2(Hs[(size_t)s * 64 + lane]);
        accx += f.x; accy += f.y;
    }

    float di = dis[node];
    float2 bb2 = *(const float2*)(b + 2 * lane);
    float ox = fmaf(accx, di, bb2.x);
    float oy = fmaf(accy, di, bb2.y);
    if (F16OUT) {
        ox = fmaxf(ox, 0.f);                 // relu folded in (next GEMM input)
        oy = fmaxf(oy, 0.f);
        ((__half2*)outv)[(size_t)node * 64 + lane] = __floats2half2_rn(ox, oy);
    } else {
        float2 o; o.x = ox; o.y = oy;
        ((float2*)((float*)outv + (size_t)node * D))[lane] = o;
    }
}

// ---------------- launch ----------------

extern "C" void kernel_launch(void* const* d_in, const int* in_sizes, int n_in,
                              void* d_out, int out_size, void* d_ws, size_t ws_size,
                              hipStream_t stream) {
    const float* x  = (const float*)d_in[0];
    const int*   ei = (const int*)d_in[1];
    const float* W1 = (const float*)d_in[2];
    const float* b1 = (const float*)d_in[3];
    const float* W2 = (const float*)d_in[4];
    const float* b2 = (const float*)d_in[5];
    const float* W3 = (const float*)d_in[6];
    const float* b3 = (const float*)d_in[7];
    float* out = (float*)d_out;

    int n = in_sizes[0] / D;
    int E = in_sizes[1] / 2;
    const int* src = ei;
    const int* dst = ei + E;
    int K = (n + NPB - 1) >> 8;     // buckets

    char* ws = (char*)d_ws;
    half_t* hbuf     = (half_t*)ws; ws += (size_t)n * D * sizeof(half_t);  // H' fp16 (25.6 MB)
    half_t* outh     = (half_t*)ws; ws += (size_t)n * D * sizeof(half_t);  // relu'd out fp16 (25.6 MB)
    float* dis       = (float*)ws;  ws += (size_t)n * sizeof(float);
    int* row_ptr     = (int*)ws;    ws += (size_t)(n + 1) * sizeof(int);
    int* csr_src     = (int*)ws;    ws += (size_t)E * sizeof(int);
    int* bucket_cnt  = (int*)ws;    ws += KMAX * sizeof(int);
    int* bucket_ptr  = (int*)ws;    ws += (KMAX + 1) * sizeof(int);
    int* bucket_cur  = (int*)ws;    ws += KMAX * sizeof(int);
    ws = (char*)(((uintptr_t)ws + 15) & ~(uintptr_t)15);   // 16B align for W packs
    half_t* Wf1      = (half_t*)ws; ws += 128 * 128 * sizeof(half_t);
    half_t* Wf2      = (half_t*)ws; ws += 128 * 128 * sizeof(half_t);
    half_t* Wf3      = (half_t*)ws; ws += 128 * 128 * sizeof(half_t);
    int* bpack       = (int*)hbuf;    // aliases hbuf (6.4 MB); dead before GEMM1 writes it

    int gC = (E + CHUNK - 1) / CHUNK; // 391
    int gM = (n + 127) / 128;         // 782 (128-row blocks)
    int gA = (n + 3) / 4;             // 25000

    // 1) bucket_cnt = 0 (stream-ordered before setup's hist atomics)
    hipMemsetAsync(bucket_cnt, 0, KMAX * sizeof(int), stream);
    // 2) setup: W packs + dst histogram in one kernel
    setup_kernel<<<98 + gC, 256, 0, stream>>>(W1, W2, W3, Wf1, Wf2, Wf3,
                                              dst, bucket_cnt, E);
    // 3-5) CSR build (packed edges)
    bucket_scan_kernel<<<1, KMAX, 0, stream>>>(bucket_cnt, bucket_ptr, bucket_cur, K, E);
    bucket_scatter_kernel<<<gC, 256, 0, stream>>>(src, dst, bucket_cur, bpack, E);
    csr_build_kernel<<<K, 256, 0, stream>>>(bpack, bucket_ptr, row_ptr, dis, csr_src, n, E, K);

    // Layer 1: H1 = fp16(dis*(x@W1)) ; out1 = relu(agg+b1) fp16
    gemm_mfma_f32in<<<gM, 256, 0, stream>>>(x, Wf1, dis, hbuf, n);
    aggregate_kernel<true><<<gA, 256, 0, stream>>>((const __half2*)hbuf, row_ptr, csr_src, dis, b1, outh, n);
    // Layer 2: H2 = fp16(dis*(out1@W2)) ; out2 = relu(agg+b2) fp16
    gemm_mfma_f16in<<<gM, 256, 0, stream>>>(outh, Wf2, dis, hbuf, n);
    aggregate_kernel<true><<<gA, 256, 0, stream>>>((const __half2*)hbuf, row_ptr, csr_src, dis, b2, outh, n);
    // Layer 3: H3 = fp16(dis*(out2@W3)) ; out = agg+b3 fp32
    gemm_mfma_f16in<<<gM, 256, 0, stream>>>(outh, Wf3, dis, hbuf, n);
    aggregate_kernel<false><<<gA, 256, 0, stream>>>((const __half2*)hbuf, row_ptr, csr_src, dis, b3, out, n);
}

// Round 10
// 412.874 us; speedup vs baseline: 1.0626x; 1.0626x over previous
//
#include <hip/hip_runtime.h>
#include <hip/hip_fp16.h>

#define D 128
#define TPAD 136         // halves; GEMM LDS row stride
#define NPB 256          // nodes per bucket (dst >> 8)
#define KMAX 512         // max buckets (n <= 131072)
#define CHUNK 4096       // edges per block in bucket passes
#define SCAP 6144        // csr_build LDS edge cap (bucket avg 4092, sd ~64)
#define SRCMASK 0x1FFFF  // low 17 bits: src id (n <= 131072)

typedef _Float16 half_t;
typedef _Float16 f16x8 __attribute__((ext_vector_type(8)));
typedef float f32x4 __attribute__((ext_vector_type(4)));

// ---------------- setup: W packs + bucket histogram in ONE kernel ----------------

__global__ __launch_bounds__(256) void setup_kernel(const float* __restrict__ W1,
                                                    const float* __restrict__ W2,
                                                    const float* __restrict__ W3,
                                                    half_t* __restrict__ Wf1,
                                                    half_t* __restrict__ Wf2,
                                                    half_t* __restrict__ Wf3,
                                                    const int* __restrict__ dst,
                                                    int* __restrict__ bucket_cnt, int E) {
    __shared__ int scnt[KMAX];
    int b = blockIdx.x, t = threadIdx.x;
    if (b < 96) {
        const float* W = (b < 32) ? W1 : (b < 64) ? W2 : W3;
        half_t* Wf = (b < 32) ? Wf1 : (b < 64) ? Wf2 : Wf3;
        int bb = b & 31;                 // 0..31 = (s, tq)
        int s = bb >> 3, tq = bb & 7;
        for (int e = t; e < 512; e += 256) {
            int l = e >> 3, j = e & 7;
            int k = s * 32 + ((l >> 4) & 3) * 4 + (j & 3) + ((j >> 2) << 4);
            int nn = tq * 16 + (l & 15);
            Wf[(size_t)((s * 8 + tq) * 64 + l) * 8 + j] = (half_t)W[k * 128 + nn];
        }
    } else if (b >= 98) {
        for (int i = t; i < KMAX; i += 256) scnt[i] = 0;
        __syncthreads();
        int base = (b - 98) * CHUNK;
        int nE = min(CHUNK, E - base);
        for (int i = t; i < nE; i += 256)
            atomicAdd(&scnt[dst[base + i] >> 8], 1);
        __syncthreads();
        for (int i = t; i < KMAX; i += 256)
            if (scnt[i]) atomicAdd(&bucket_cnt[i], scnt[i]);
    }
}

// Exclusive scan of bucket_cnt[K] -> bucket_ptr[K+1], bucket_cur[K]=bucket_ptr[K]
__global__ __launch_bounds__(KMAX) void bucket_scan_kernel(const int* __restrict__ bucket_cnt,
                                                           int* __restrict__ bucket_ptr,
                                                           int* __restrict__ bucket_cur,
                                                           int K, int E) {
    __shared__ int sh[KMAX];
    int t = threadIdx.x;
    int v = (t < K) ? bucket_cnt[t] : 0;
    sh[t] = v;
    __syncthreads();
    for (int off = 1; off < KMAX; off <<= 1) {
        int add = (t >= off) ? sh[t - off] : 0;
        __syncthreads();
        sh[t] += add;
        __syncthreads();
    }
    if (t < K) {
        int ex = sh[t] - v;
        bucket_ptr[t] = ex;
        bucket_cur[t] = ex;
    }
    if (t == 0) bucket_ptr[K] = E;
}

// bpack (R14-kept): ONE int per edge: src | (dst&255)<<17 — halves partition traffic.
__global__ __launch_bounds__(256) void bucket_scatter_kernel(const int* __restrict__ src,
                                                             const int* __restrict__ dst,
                                                             int* __restrict__ bucket_cur,
                                                             int* __restrict__ bpack, int E) {
    __shared__ int sdst[CHUNK];     // 16 KB
    __shared__ int scnt[KMAX];      // 2 KB
    __shared__ int sbase[KMAX];     // 2 KB
    int t = threadIdx.x;
    int base = blockIdx.x * CHUNK;
    int nE = min(CHUNK, E - base);
    for (int i = t; i < KMAX; i += 256) scnt[i] = 0;
    __syncthreads();
    for (int i = t; i < nE; i += 256) {
        int d = dst[base + i];
        sdst[i] = d;
        atomicAdd(&scnt[d >> 8], 1);
    }
    __syncthreads();
    for (int i = t; i < KMAX; i += 256) {
        int c = scnt[i];
        sbase[i] = c ? atomicAdd(&bucket_cur[i], c) : 0;
        scnt[i] = 0;                // reuse as local cursor
    }
    __syncthreads();
    for (int i = t; i < nE; i += 256) {
        int d = sdst[i];
        int b = d >> 8;
        int pos = sbase[b] + atomicAdd(&scnt[b], 1);
        bpack[pos] = src[base + i] | ((d & 255) << 17);
    }
}

// Fused count+scan+fill on packed edges (LDS 26 KB).
__global__ __launch_bounds__(256) void csr_build_kernel(const int* __restrict__ bpack,
                                                        const int* __restrict__ bucket_ptr,
                                                        int* __restrict__ row_ptr,
                                                        float* __restrict__ dis,
                                                        int* __restrict__ csr_src,
                                                        int n, int E, int K) {
    __shared__ int scnt[NPB];
    __shared__ int sh[NPB];
    __shared__ int sedge[SCAP];     // 24 KB
    int b = blockIdx.x;
    int node0 = b << 8;
    int nn = min(NPB, n - node0);
    int t = threadIdx.x;
    int p0 = bucket_ptr[b], p1 = bucket_ptr[b + 1];
    int cnt = p1 - p0;
    bool stage = (cnt <= SCAP);     // wave-uniform
    scnt[t] = 0;
    __syncthreads();
    for (int i = t; i < cnt; i += 256) {
        int e = bpack[p0 + i];
        if (stage) sedge[i] = e;
        atomicAdd(&scnt[(e >> 17) & 255], 1);
    }
    __syncthreads();
    int v = scnt[t];
    sh[t] = v;
    __syncthreads();
    for (int off = 1; off < NPB; off <<= 1) {
        int add = (t >= off) ? sh[t - off] : 0;
        __syncthreads();
        sh[t] += add;
        __syncthreads();
    }
    int rowbase = p0 + sh[t] - v;   // exclusive
    if (t < nn) {
        row_ptr[node0 + t] = rowbase;
        dis[node0 + t] = rsqrtf((float)(v + 1)); // +1 self-loop
    }
    if (b == K - 1 && t == 0) row_ptr[n] = E;
    scnt[t] = rowbase;              // reuse as cursor
    __syncthreads();
    for (int i = t; i < cnt; i += 256) {
        int e = stage ? sedge[i] : bpack[p0 + i];
        int pos = atomicAdd(&scnt[(e >> 17) & 255], 1);
        csr_src[pos] = e & SRCMASK;
    }
}

// ---------------- GEMM (MFMA): C[n x 128] = fp16( dis[row] * (A @ W) ) ----------
// R13-proven 64-row tile (17 KB LDS, high residency). LDS-bounce epilogue,
// contiguous float4 stores. (R14's 128-row tile regressed: occupancy loss.)

__device__ __forceinline__ void gemm_core_epilogue(half_t* sA, int tid, int base,
                                                   const float* __restrict__ dis,
                                                   half_t* __restrict__ C, int n,
                                                   f32x4 acc[8], int l, int w) {
    int m = l & 15, g = l >> 4;
    int R = w * 16;
    int row0 = base + R + 4 * g;
    float dd[4];
#pragma unroll
    for (int r = 0; r < 4; ++r) dd[r] = (row0 + r < n) ? dis[row0 + r] : 0.f;
    __syncthreads();            // all frag reads done before clobbering sA
#pragma unroll
    for (int t = 0; t < 8; ++t) {
#pragma unroll
        for (int r = 0; r < 4; ++r)
            sA[(R + 4 * g + r) * TPAD + t * 16 + m] = (half_t)(acc[t][r] * dd[r]);
    }
    __syncthreads();
#pragma unroll
    for (int q = 0; q < 4; ++q) {
        int f4 = q * 256 + tid;         // 0..1023 ; 16 float4 per row, 64 rows
        int r = f4 >> 4, c = f4 & 15;
        int row = base + r;
        if (row < n)
            *(float4*)&C[(size_t)row * D + c * 8] = *(const float4*)&sA[r * TPAD + c * 8];
    }
}

__device__ __forceinline__ void gemm_mfma_loop(const half_t* sA, const half_t* __restrict__ Wf,
                                               f32x4 acc[8], int l, int w) {
    int m = l & 15, g = l >> 4;
    int R = w * 16;
    const f16x8* WF = (const f16x8*)Wf;
#pragma unroll
    for (int s = 0; s < 4; ++s) {        // K steps of 32
        union { f16x8 v; float2 f2[2]; } af;
        int a_off = (R + m) * TPAD + s * 32 + 4 * g;
        af.f2[0] = *(const float2*)&sA[a_off];        // k +0..3
        af.f2[1] = *(const float2*)&sA[a_off + 16];   // k +16..19
#pragma unroll
        for (int t = 0; t < 8; ++t) {
            f16x8 bf = WF[(size_t)(s * 8 + t) * 64 + l];
            acc[t] = __builtin_amdgcn_mfma_f32_16x16x32_f16(af.v, bf, acc[t], 0, 0, 0);
        }
    }
}

__global__ __launch_bounds__(256) void gemm_mfma_f32in(const float* __restrict__ A,
                                                       const half_t* __restrict__ Wf,
                                                       const float* __restrict__ dis,
                                                       half_t* __restrict__ C, int n) {
    __shared__ half_t sA[64 * TPAD];
    int tid = threadIdx.x;
    int base = blockIdx.x * 64;

    const float4* A4 = (const float4*)A;     // row stride = 32 float4
#pragma unroll
    for (int it = 0; it < 8; ++it) {
        int idx = it * 256 + tid;            // 0..2047
        int r = idx >> 5, kq = idx & 31;
        int grow = base + r;
        float4 va = (grow < n) ? A4[(size_t)grow * 32 + kq]
                               : make_float4(0.f, 0.f, 0.f, 0.f);
        union { half_t h[4]; float2 f2; } pk;
        pk.h[0] = (half_t)va.x; pk.h[1] = (half_t)va.y;
        pk.h[2] = (half_t)va.z; pk.h[3] = (half_t)va.w;
        *(float2*)&sA[r * TPAD + kq * 4] = pk.f2;
    }
    __syncthreads();

    int l = tid & 63, w = tid >> 6;
    f32x4 acc[8];
#pragma unroll
    for (int t = 0; t < 8; ++t) acc[t] = (f32x4){0.f, 0.f, 0.f, 0.f};
    gemm_mfma_loop(sA, Wf, acc, l, w);
    gemm_core_epilogue(sA, tid, base, dis, C, n, acc, l, w);
}

__global__ __launch_bounds__(256) void gemm_mfma_f16in(const half_t* __restrict__ A,
                                                       const half_t* __restrict__ Wf,
                                                       const float* __restrict__ dis,
                                                       half_t* __restrict__ C, int n) {
    __shared__ half_t sA[64 * TPAD];
    int tid = threadIdx.x;
    int base = blockIdx.x * 64;

    const float4* A4 = (const float4*)A;     // fp16 row = 16 float4
#pragma unroll
    for (int it = 0; it < 4; ++it) {
        int idx = it * 256 + tid;            // 0..1023
        int r = idx >> 4, c16 = idx & 15;
        int grow = base + r;
        float4 va = (grow < n) ? A4[(size_t)grow * 16 + c16]
                               : make_float4(0.f, 0.f, 0.f, 0.f);
        *(float4*)&sA[r * TPAD + c16 * 8] = va;
    }
    __syncthreads();

    int l = tid & 63, w = tid >> 6;
    f32x4 acc[8];
#pragma unroll
    for (int t = 0; t < 8; ++t) acc[t] = (f32x4){0.f, 0.f, 0.f, 0.f};
    gemm_mfma_loop(sA, Wf, acc, l, w);
    gemm_core_epilogue(sA, tid, base, dis, C, n, acc, l, w);
}

// ---------------- Aggregation: out[i] = dis_i*(H'[i] + sum_e H'[src_e]) + b ----------
// R11-proven. F16OUT: write relu'd fp16 (layers 1-2).

template <bool F16OUT>
__global__ __launch_bounds__(256) void aggregate_kernel(const __half2* __restrict__ Hs,
                                                        const int* __restrict__ row_ptr,
                                                        const int* __restrict__ csr_src,
                                                        const float* __restrict__ dis,
                                                        const float* __restrict__ b,
                                                        void* __restrict__ outv, int n) {
    int node = blockIdx.x * 4 + (threadIdx.x >> 6);
    if (node >= n) return;
    int lane = threadIdx.x & 63;

    float2 s0 = __half22float2(Hs[(size_t)node * 64 + lane]);
    float accx = s0.x, accy = s0.y;                     // self-loop term H'[i]

    int p0 = row_ptr[node], p1 = row_ptr[node + 1];
    int p = p0;
    int nb8 = (p1 - p0) >> 3;
    if (nb8 > 0) {
        int idx[8];
#pragma unroll
        for (int u = 0; u < 8; ++u) idx[u] = csr_src[p + u];
        for (int bb = 1; bb < nb8; ++bb) {
            int nxt[8];
#pragma unroll
            for (int u = 0; u < 8; ++u) nxt[u] = csr_src[p + 8 + u];   // prefetch
            __half2 v[8];
#pragma unroll
            for (int u = 0; u < 8; ++u) v[u] = Hs[(size_t)idx[u] * 64 + lane];
#pragma unroll
            for (int u = 0; u < 8; ++u) {
                float2 f = __half22float2(v[u]);
                accx += f.x; accy += f.y;
            }
#pragma unroll
            for (int u = 0; u < 8; ++u) idx[u] = nxt[u];
            p += 8;
        }
        {
            __half2 v[8];
#pragma unroll
            for (int u = 0; u < 8; ++u) v[u] = Hs[(size_t)idx[u] * 64 + lane];
#pragma unroll
            for (int u = 0; u < 8; ++u) {
                float2 f = __half22float2(v[u]);
                accx += f.x; accy += f.y;
            }
            p += 8;
        }
    }
    for (; p + 4 <= p1; p += 4) {
        int s0i = csr_src[p + 0];
        int s1i = csr_src[p + 1];
        int s2i = csr_src[p + 2];
        int s3i = csr_src[p + 3];
        __half2 v0 = Hs[(size_t)s0i * 64 + lane];
        __half2 v1 = Hs[(size_t)s1i * 64 + lane];
        __half2 v2 = Hs[(size_t)s2i * 64 + lane];
        __half2 v3 = Hs[(size_t)s3i * 64 + lane];
        float2 f0 = __half22float2(v0), f1 = __half22float2(v1);
        float2 f2 = __half22float2(v2), f3 = __half22float2(v3);
        accx += f0.x; accy += f0.y;
        accx += f1.x; accy += f1.y;
        accx += f2.x; accy += f2.y;
        accx += f3.x; accy += f3.y;
    }
    for (; p < p1; ++p) {
        int s = csr_src[p];
        float2 f = __half22float2(Hs[(size_t)s * 64 + lane]);
        accx += f.x; accy += f.y;
    }

    float di = dis[node];
    float2 bb2 = *(const float2*)(b + 2 * lane);
    float ox = fmaf(accx, di, bb2.x);
    float oy = fmaf(accy, di, bb2.y);
    if (F16OUT) {
        ox = fmaxf(ox, 0.f);                 // relu folded in (next GEMM input)
        oy = fmaxf(oy, 0.f);
        ((__half2*)outv)[(size_t)node * 64 + lane] = __floats2half2_rn(ox, oy);
    } else {
        float2 o; o.x = ox; o.y = oy;
        ((float2*)((float*)outv + (size_t)node * D))[lane] = o;
    }
}

// ---------------- launch ----------------

extern "C" void kernel_launch(void* const* d_in, const int* in_sizes, int n_in,
                              void* d_out, int out_size, void* d_ws, size_t ws_size,
                              hipStream_t stream) {
    const float* x  = (const float*)d_in[0];
    const int*   ei = (const int*)d_in[1];
    const float* W1 = (const float*)d_in[2];
    const float* b1 = (const float*)d_in[3];
    const float* W2 = (const float*)d_in[4];
    const float* b2 = (const float*)d_in[5];
    const float* W3 = (const float*)d_in[6];
    const float* b3 = (const float*)d_in[7];
    float* out = (float*)d_out;

    int n = in_sizes[0] / D;
    int E = in_sizes[1] / 2;
    const int* src = ei;
    const int* dst = ei + E;
    int K = (n + NPB - 1) >> 8;     // buckets

    char* ws = (char*)d_ws;
    half_t* hbuf     = (half_t*)ws; ws += (size_t)n * D * sizeof(half_t);  // H' fp16 (25.6 MB)
    half_t* outh     = (half_t*)ws; ws += (size_t)n * D * sizeof(half_t);  // relu'd out fp16 (25.6 MB)
    float* dis       = (float*)ws;  ws += (size_t)n * sizeof(float);
    int* row_ptr     = (int*)ws;    ws += (size_t)(n + 1) * sizeof(int);
    int* csr_src     = (int*)ws;    ws += (size_t)E * sizeof(int);
    int* bucket_cnt  = (int*)ws;    ws += KMAX * sizeof(int);
    int* bucket_ptr  = (int*)ws;    ws += (KMAX + 1) * sizeof(int);
    int* bucket_cur  = (int*)ws;    ws += KMAX * sizeof(int);
    ws = (char*)(((uintptr_t)ws + 15) & ~(uintptr_t)15);   // 16B align for W packs
    half_t* Wf1      = (half_t*)ws; ws += 128 * 128 * sizeof(half_t);
    half_t* Wf2      = (half_t*)ws; ws += 128 * 128 * sizeof(half_t);
    half_t* Wf3      = (half_t*)ws; ws += 128 * 128 * sizeof(half_t);
    int* bpack       = (int*)hbuf;    // aliases hbuf (6.4 MB); dead before GEMM1 writes it

    int gC = (E + CHUNK - 1) / CHUNK; // 391
    int gM = (n + 63) / 64;           // 1563 (64-row blocks)
    int gA = (n + 3) / 4;             // 25000

    // 1) bucket_cnt = 0 (stream-ordered before setup's hist atomics)
    hipMemsetAsync(bucket_cnt, 0, KMAX * sizeof(int), stream);
    // 2) setup: W packs + dst histogram in one kernel
    setup_kernel<<<98 + gC, 256, 0, stream>>>(W1, W2, W3, Wf1, Wf2, Wf3,
                                              dst, bucket_cnt, E);
    // 3-5) CSR build (packed edges)
    bucket_scan_kernel<<<1, KMAX, 0, stream>>>(bucket_cnt, bucket_ptr, bucket_cur, K, E);
    bucket_scatter_kernel<<<gC, 256, 0, stream>>>(src, dst, bucket_cur, bpack, E);
    csr_build_kernel<<<K, 256, 0, stream>>>(bpack, bucket_ptr, row_ptr, dis, csr_src, n, E, K);

    // Layer 1: H1 = fp16(dis*(x@W1)) ; out1 = relu(agg+b1) fp16
    gemm_mfma_f32in<<<gM, 256, 0, stream>>>(x, Wf1, dis, hbuf, n);
    aggregate_kernel<true><<<gA, 256, 0, stream>>>((const __half2*)hbuf, row_ptr, csr_src, dis, b1, outh, n);
    // Layer 2: H2 = fp16(dis*(out1@W2)) ; out2 = relu(agg+b2) fp16
    gemm_mfma_f16in<<<gM, 256, 0, stream>>>(outh, Wf2, dis, hbuf, n);
    aggregate_kernel<true><<<gA, 256, 0, stream>>>((const __half2*)hbuf, row_ptr, csr_src, dis, b2, outh, n);
    // Layer 3: H3 = fp16(dis*(out2@W3)) ; out = agg+b3 fp32
    gemm_mfma_f16in<<<gM, 256, 0, stream>>>(outh, Wf3, dis, hbuf, n);
    aggregate_kernel<false><<<gA, 256, 0, stream>>>((const __half2*)hbuf, row_ptr, csr_src, dis, b3, out, n);
}